// Round 5
// baseline (25629.535 us; speedup 1.0000x reference)
//
#include <hip/hip_runtime.h>
#include <math.h>

// Seq2Seq decoder, fp32 VALU implementation v2 (R1 structure, LDS-optimized).
//  - Encoder is dead code (reference discards it); decoder needs only tags,
//    l2_* weights, lin_W/b, START=1.
//  - R1 (verified PASS) was LDS-pipe-bound: 4x8 tiles = 0.375 LDS-floats/FMA
//    + 4-way staging-write conflicts. v2: 8x8 tiles (0.25 fl/FMA), padded
//    [k][m] LDS (stride 132/68: 16B-aligned b128 reads, <=2-way read
//    conflicts), fused lin+sigmoid+argmax kernel.
//  - All math fp32 (bit-compatible with R1's verified numerics).

constexpr int Bsz   = 4096;
constexpr int AA    = 256;
constexpr int STEPS = 30;
constexpr int LDP   = 31 * AA;                      // 7936
constexpr long long BH = (long long)Bsz * AA;       // one [B,256] buffer
constexpr long long PROB_N = (long long)Bsz * 31 * AA;

__device__ __forceinline__ float sigf(float x) { return 1.0f / (1.0f + expf(-x)); }

// ---------------------------------------------------------------------------
// init: zero h(parity0, 3 layers) and c(3 layers); one-hot(START=1) into
// probabilities[:, 0, :].  (identical to R1 - verified)
// ---------------------------------------------------------------------------
__global__ void init_kernel(float* __restrict__ out, float* __restrict__ h0,
                            float* __restrict__ c0) {
    int idx = blockIdx.x * 256 + threadIdx.x;   // < 4096*256
    #pragma unroll
    for (int l = 0; l < 3; l++) {
        h0[(long long)l * BH + idx] = 0.f;
        c0[(long long)l * BH + idx] = 0.f;
    }
    int row = idx >> 8, col = idx & 255;
    out[(long long)row * LDP + col] = (col == 1) ? 1.0f : 0.0f;
}

// ---------------------------------------------------------------------------
// Fused GEMM + LSTM cell. Tile: BM=128 rows x BN=64 gate-cols per block,
// 128 threads, 8x8 per thread. Gate-cols interleaved (n = j*4+gate locally)
// so each thread owns all 4 gates of 2 hidden units -> self-contained cell.
// LDS [k][m] padded to 132/68 floats: b128 compute reads 16B-aligned and
// <=2-way bank aliased (free); staging writes scalar (4-way, ~11% of LDS ops).
// grid = (4096/128, 1024/64) = (32, 16).
// ---------------------------------------------------------------------------
__global__ __launch_bounds__(128) void lstm_gemm(
    const float* __restrict__ x0, int ldx0, int k0, const float* __restrict__ w0, int ldw0,
    const float* __restrict__ x1, int ldx1, int k1, const float* __restrict__ w1, int ldw1,
    const float* __restrict__ x2, int ldx2, int k2, const float* __restrict__ w2, int ldw2,
    const float* __restrict__ b1, const float* __restrict__ b2,
    float* __restrict__ cbuf, float* __restrict__ hout)
{
    __shared__ float xs[32][132];   // [k][m], stride 132: 16B-aligned rows
    __shared__ float ws[32][68];    // [k][n]

    const int tid = threadIdx.x;
    const int tx = tid & 7;         // 8 col-groups of 8
    const int ty = tid >> 3;        // 16 row-groups of 8
    const int m0 = blockIdx.x * 128;
    const int j0 = blockIdx.y * 16; // 16 hidden units per block (x4 gates = 64 cols)

    float acc[8][8];
    #pragma unroll
    for (int r = 0; r < 8; r++)
        #pragma unroll
        for (int c = 0; c < 8; c++) acc[r][c] = 0.f;

    const float* Xs[3]   = {x0, x1, x2};
    const float* Ws[3]   = {w0, w1, w2};
    const int    ldxs[3] = {ldx0, ldx1, ldx2};
    const int    ldws[3] = {ldw0, ldw1, ldw2};
    const int    Ks[3]   = {k0, k1, k2};

    for (int s = 0; s < 3; s++) {
        const int K = Ks[s];
        if (K == 0) continue;
        const float* X = Xs[s];
        const float* W = Ws[s];
        const long long ldx = ldxs[s], ldw = ldws[s];

        for (int kk = 0; kk < K; kk += 32) {
            // stage X: 128 m x 32 k (consecutive tid -> consecutive k: coalesced)
            #pragma unroll
            for (int i = 0; i < 32; i++) {
                int e = tid + i * 128;
                int m = e >> 5, k = e & 31;
                xs[k][m] = X[(long long)(m0 + m) * ldx + kk + k];
            }
            // stage W: 64 n x 32 k; source row = gate-interleaved
            #pragma unroll
            for (int i = 0; i < 16; i++) {
                int e = tid + i * 128;
                int n = e >> 5, k = e & 31;
                int r = (n & 3) * AA + j0 + (n >> 2);
                ws[k][n] = W[(long long)r * ldw + kk + k];
            }
            __syncthreads();
            #pragma unroll 4
            for (int k = 0; k < 32; k++) {
                float4 xa = *reinterpret_cast<const float4*>(&xs[k][ty * 8]);
                float4 xb = *reinterpret_cast<const float4*>(&xs[k][ty * 8 + 4]);
                float4 wa = *reinterpret_cast<const float4*>(&ws[k][tx * 8]);
                float4 wb = *reinterpret_cast<const float4*>(&ws[k][tx * 8 + 4]);
                float xr[8] = {xa.x, xa.y, xa.z, xa.w, xb.x, xb.y, xb.z, xb.w};
                float wr[8] = {wa.x, wa.y, wa.z, wa.w, wb.x, wb.y, wb.z, wb.w};
                #pragma unroll
                for (int r = 0; r < 8; r++)
                    #pragma unroll
                    for (int c = 0; c < 8; c++)
                        acc[r][c] = fmaf(xr[r], wr[c], acc[r][c]);
            }
            __syncthreads();
        }
    }

    // epilogue: thread owns rows m0+ty*8..+8, hidden units j0+tx*2, j0+tx*2+1
    #pragma unroll
    for (int r = 0; r < 8; r++) {
        int row = m0 + ty * 8 + r;
        #pragma unroll
        for (int hu = 0; hu < 2; hu++) {
            int j = j0 + tx * 2 + hu;
            int cb = hu * 4;
            float gi = acc[r][cb + 0] + b1[0 * AA + j] + b2[0 * AA + j];
            float gf = acc[r][cb + 1] + b1[1 * AA + j] + b2[1 * AA + j];
            float gg = acc[r][cb + 2] + b1[2 * AA + j] + b2[2 * AA + j];
            float go = acc[r][cb + 3] + b1[3 * AA + j] + b2[3 * AA + j];
            long long co = (long long)row * AA + j;
            float cn = sigf(gf) * cbuf[co] + sigf(gi) * tanhf(gg);
            cbuf[co] = cn;
            hout[co] = sigf(go) * tanhf(cn);
        }
    }
}

// ---------------------------------------------------------------------------
// Fused lin + sigmoid + argmax. Tile: 32 rows x all 256 cols per block.
// 256 threads: tx = tid&31 (col-group of 8), ty = tid>>5 (row-group of 4).
// Writes probabilities[:, t+1, :] and outputs[:, t]. First-index tie rule
// (ascending scan, strict >) matches numpy argmax.
// ---------------------------------------------------------------------------
__global__ __launch_bounds__(256) void lin_argmax(
    const float* __restrict__ h2, const float* __restrict__ linW,
    const float* __restrict__ linb,
    float* __restrict__ out, float* __restrict__ outbuf, int t)
{
    __shared__ float xs[32][36];    // [k][m] (pad 36: 16B-aligned rows)
    __shared__ float ws[32][260];   // [k][n]
    __shared__ float rv[32][32];
    __shared__ int   ri[32][32];

    const int tid = threadIdx.x;
    const int tx = tid & 31;
    const int ty = tid >> 5;
    const int m0 = blockIdx.x * 32;

    float acc[4][8];
    #pragma unroll
    for (int r = 0; r < 4; r++)
        #pragma unroll
        for (int c = 0; c < 8; c++) acc[r][c] = 0.f;

    for (int kk = 0; kk < AA; kk += 32) {
        #pragma unroll
        for (int i = 0; i < 4; i++) {
            int e = tid + i * 256;
            int m = e >> 5, k = e & 31;
            xs[k][m] = h2[(long long)(m0 + m) * AA + kk + k];
        }
        #pragma unroll
        for (int i = 0; i < 32; i++) {
            int e = tid + i * 256;
            int n = e >> 5, k = e & 31;
            ws[k][n] = linW[(long long)n * AA + kk + k];
        }
        __syncthreads();
        #pragma unroll 4
        for (int k = 0; k < 32; k++) {
            float4 xv = *reinterpret_cast<const float4*>(&xs[k][ty * 4]);
            float4 wa = *reinterpret_cast<const float4*>(&ws[k][tx * 8]);
            float4 wb = *reinterpret_cast<const float4*>(&ws[k][tx * 8 + 4]);
            float xr[4] = {xv.x, xv.y, xv.z, xv.w};
            float wr[8] = {wa.x, wa.y, wa.z, wa.w, wb.x, wb.y, wb.z, wb.w};
            #pragma unroll
            for (int r = 0; r < 4; r++)
                #pragma unroll
                for (int c = 0; c < 8; c++)
                    acc[r][c] = fmaf(xr[r], wr[c], acc[r][c]);
        }
        __syncthreads();
    }

    // sigmoid + store probs + per-thread argmax over its 8 cols
    #pragma unroll
    for (int r = 0; r < 4; r++) {
        int row = m0 + ty * 4 + r;
        float bv = -1.0f; int bi = 0;
        #pragma unroll
        for (int c = 0; c < 8; c++) {
            int col = tx * 8 + c;
            float v = sigf(acc[r][c] + linb[col]);
            out[(long long)row * LDP + (long long)(t + 1) * AA + col] = v;
            if (v > bv) { bv = v; bi = col; }      // ascending c: first max
        }
        rv[ty * 4 + r][tx] = bv;
        ri[ty * 4 + r][tx] = bi;
    }
    __syncthreads();
    if (tid < 32) {
        float bv = rv[tid][0]; int bi = ri[tid][0];
        #pragma unroll 8
        for (int x = 1; x < 32; x++) {             // ascending tx: first max
            float v = rv[tid][x];
            if (v > bv) { bv = v; bi = ri[tid][x]; }
        }
        outbuf[(long long)(m0 + tid) * STEPS + t] = (float)bi;
    }
}

// ---------------------------------------------------------------------------
extern "C" void kernel_launch(void* const* d_in, const int* in_sizes, int n_in,
                              void* d_out, int out_size, void* d_ws, size_t ws_size,
                              hipStream_t stream) {
    const float* tags  = (const float*)d_in[2];
    const float* Wih0  = (const float*)d_in[13];  // [1024, 384]
    const float* Whh0  = (const float*)d_in[14];  // [1024, 256]
    const float* bih0  = (const float*)d_in[15];
    const float* bhh0  = (const float*)d_in[16];
    const float* Wih12 = (const float*)d_in[17];  // [2, 1024, 256]
    const float* Whh12 = (const float*)d_in[18];
    const float* bih12 = (const float*)d_in[19];  // [2, 1024]
    const float* bhh12 = (const float*)d_in[20];
    const float* linW  = (const float*)d_in[21];  // [256, 256]
    const float* linb  = (const float*)d_in[22];

    float* out  = (float*)d_out;
    float* wsp  = (float*)d_ws;
    float* hbuf = wsp;                        // [2 parity][3 layer][B*256]
    float* cbuf = wsp + 6 * BH;               // [3 layer][B*256]
    float* outputs = out + PROB_N;

    init_kernel<<<Bsz, 256, 0, stream>>>(out, hbuf, cbuf);

    for (int t = 0; t < STEPS; t++) {
        int p = t & 1, q = 1 - p;
        float* hp = hbuf + (long long)p * 3 * BH;
        float* hq = hbuf + (long long)q * 3 * BH;
        const float* prob = out + (long long)t * AA;   // probabilities[:, t, :]

        // layer 0: gates = [prob,tags] @ Wih0^T + h @ Whh0^T + b
        lstm_gemm<<<dim3(32, 16), 128, 0, stream>>>(
            prob, LDP, AA, Wih0, AA + 128,
            tags, 128, 128, Wih0 + AA, AA + 128,
            hp + 0 * BH, AA, AA, Whh0, AA,
            bih0, bhh0,
            cbuf + 0 * BH, hq + 0 * BH);
        // layer 1
        lstm_gemm<<<dim3(32, 16), 128, 0, stream>>>(
            hq + 0 * BH, AA, AA, Wih12, AA,
            nullptr, 0, 0, nullptr, 0,
            hp + 1 * BH, AA, AA, Whh12, AA,
            bih12, bhh12,
            cbuf + 1 * BH, hq + 1 * BH);
        // layer 2
        lstm_gemm<<<dim3(32, 16), 128, 0, stream>>>(
            hq + 1 * BH, AA, AA, Wih12 + (long long)4 * AA * AA, AA,
            nullptr, 0, 0, nullptr, 0,
            hp + 2 * BH, AA, AA, Whh12 + (long long)4 * AA * AA, AA,
            bih12 + 4 * AA, bhh12 + 4 * AA,
            cbuf + 2 * BH, hq + 2 * BH);
        // lin + sigmoid + argmax -> probabilities[:, t+1, :], outputs[:, t]
        lin_argmax<<<Bsz / 32, 256, 0, stream>>>(
            hq + 2 * BH, linW, linb, out, outputs, t);
    }
}